// Round 1
// baseline (540.934 us; speedup 1.0000x reference)
//
#include <hip/hip_runtime.h>

constexpr int N_NODES = 100000;
constexpr int E_EDGES = 1600000;
constexpr int NBLK    = (N_NODES + 1023) / 1024;   // 98 scan blocks

// ---------------------------------------------------------------------------
// GEMM: h[N,128] = feat[N,128] @ W[128,128]^T
// 256 threads/block, 32 rows/block, full 128-col width.
// LDS: Wt[k][c] 64KB (k-major) + ft[k][r] 16KB  -> 80KB -> 2 blocks/CU.
// Per k: b = Wt[k][4tc..] (contiguous 512B wave read, conflict-free),
//        a = ft[k][4tr..] (2 distinct addrs/wave -> broadcast), 16 FMA/thread.
// ---------------------------------------------------------------------------
__global__ __launch_bounds__(256, 2) void k_gemm(const float* __restrict__ feat,
                                                 const float* __restrict__ W,
                                                 float* __restrict__ h) {
    __shared__ float Wt[128 * 128];  // Wt[k*128 + c]
    __shared__ float ft[128 * 32];   // ft[k*32 + r]
    const int tid = threadIdx.x;
    const int row0 = blockIdx.x * 32;

    // stage W transposed: lanes write consecutive c -> conflict-free
#pragma unroll
    for (int m = 0; m < 16; ++m) {
        int chunk = m * 256 + tid;
        int c = chunk & 127;
        int kq = chunk >> 7;
        float4 w = reinterpret_cast<const float4*>(W)[c * 32 + kq];
        Wt[(4 * kq + 0) * 128 + c] = w.x;
        Wt[(4 * kq + 1) * 128 + c] = w.y;
        Wt[(4 * kq + 2) * 128 + c] = w.z;
        Wt[(4 * kq + 3) * 128 + c] = w.w;
    }
    // stage feat tile transposed: lanes write consecutive r -> conflict-free
#pragma unroll
    for (int m = 0; m < 4; ++m) {
        int chunk = m * 256 + tid;
        int r = chunk & 31;
        int kq = chunk >> 5;
        float4 f = reinterpret_cast<const float4*>(feat)[(size_t)(row0 + r) * 32 + kq];
        ft[(4 * kq + 0) * 32 + r] = f.x;
        ft[(4 * kq + 1) * 32 + r] = f.y;
        ft[(4 * kq + 2) * 32 + r] = f.z;
        ft[(4 * kq + 3) * 32 + r] = f.w;
    }
    __syncthreads();

    const int tc = tid & 31;   // col group: cols 4tc..4tc+3
    const int tr = tid >> 5;   // row group: rows 4tr..4tr+3
    float acc[4][4] = {};

#pragma unroll 4
    for (int k = 0; k < 128; ++k) {
        float4 bv = *reinterpret_cast<const float4*>(&Wt[k * 128 + tc * 4]);
        float4 av = *reinterpret_cast<const float4*>(&ft[k * 32 + tr * 4]);
        float a[4] = {av.x, av.y, av.z, av.w};
        float b[4] = {bv.x, bv.y, bv.z, bv.w};
#pragma unroll
        for (int r = 0; r < 4; ++r)
#pragma unroll
            for (int c = 0; c < 4; ++c)
                acc[r][c] += a[r] * b[c];
    }

#pragma unroll
    for (int r = 0; r < 4; ++r) {
        float4 o = make_float4(acc[r][0], acc[r][1], acc[r][2], acc[r][3]);
        *reinterpret_cast<float4*>(&h[(size_t)(row0 + tr * 4 + r) * 128 + tc * 4]) = o;
    }
}

// ---------------------------------------------------------------------------
// el/er: per (node, head) dot of h row-slice with attn vectors
// ---------------------------------------------------------------------------
__global__ void k_el_er(const float* __restrict__ h,
                        const float* __restrict__ attn_l,
                        const float* __restrict__ attn_r,
                        float* __restrict__ el, float* __restrict__ er) {
    int t = blockIdx.x * blockDim.x + threadIdx.x;
    if (t >= N_NODES * 4) return;
    int g = t & 3;
    int n = t >> 2;
    const float4* hp = reinterpret_cast<const float4*>(h + (size_t)n * 128 + g * 32);
    const float4* al = reinterpret_cast<const float4*>(attn_l + g * 32);
    const float4* ar = reinterpret_cast<const float4*>(attn_r + g * 32);
    float sl = 0.f, sr = 0.f;
#pragma unroll
    for (int q = 0; q < 8; ++q) {
        float4 hv = hp[q];
        float4 a = al[q];
        float4 b = ar[q];
        sl += hv.x * a.x + hv.y * a.y + hv.z * a.z + hv.w * a.w;
        sr += hv.x * b.x + hv.y * b.y + hv.z * b.z + hv.w * b.w;
    }
    el[t] = sl;
    er[t] = sr;
}

// ---------------------------------------------------------------------------
// counting sort of edges by dst: histogram -> exclusive scan -> scatter
// ---------------------------------------------------------------------------
__global__ void k_hist(const int* __restrict__ dst, int* __restrict__ deg) {
    int e = blockIdx.x * blockDim.x + threadIdx.x;
    if (e < E_EDGES) atomicAdd(&deg[dst[e]], 1);
}

__global__ void k_bsum(const int* __restrict__ deg, int* __restrict__ aux) {
    int tid = threadIdx.x;
    int i0 = blockIdx.x * 1024 + tid * 4;
    int sum = 0;
#pragma unroll
    for (int j = 0; j < 4; ++j)
        if (i0 + j < N_NODES) sum += deg[i0 + j];
#pragma unroll
    for (int m = 32; m; m >>= 1) sum += __shfl_xor(sum, m, 64);
    __shared__ int wsums[4];
    if ((tid & 63) == 0) wsums[tid >> 6] = sum;
    __syncthreads();
    if (tid == 0) aux[blockIdx.x] = wsums[0] + wsums[1] + wsums[2] + wsums[3];
}

__global__ void k_scanaux(int* __restrict__ aux) {
    __shared__ int s[128];
    int i = threadIdx.x;
    int v = (i < NBLK) ? aux[i] : 0;
    s[i] = v;
    __syncthreads();
#pragma unroll
    for (int d = 1; d < 128; d <<= 1) {
        int t = (i >= d) ? s[i - d] : 0;
        __syncthreads();
        s[i] += t;
        __syncthreads();
    }
    if (i < NBLK) aux[i] = s[i] - v;  // exclusive
}

__global__ void k_bscan(const int* __restrict__ deg, const int* __restrict__ aux,
                        int* __restrict__ start, int* __restrict__ cursor) {
    int tid = threadIdx.x;
    int lane = tid & 63;
    int wid = tid >> 6;
    int i0 = blockIdx.x * 1024 + tid * 4;
    int v[4];
#pragma unroll
    for (int j = 0; j < 4; ++j)
        v[j] = (i0 + j < N_NODES) ? deg[i0 + j] : 0;
    int tsum = v[0] + v[1] + v[2] + v[3];
    int x = tsum;
#pragma unroll
    for (int d = 1; d < 64; d <<= 1) {
        int t = __shfl_up(x, d, 64);
        if (lane >= d) x += t;
    }
    __shared__ int wsums[4];
    if (lane == 63) wsums[wid] = x;
    __syncthreads();
    int base = aux[blockIdx.x];
#pragma unroll
    for (int w = 0; w < 4; ++w)
        if (w < wid) base += wsums[w];
    int p = base + x - tsum;  // exclusive prefix for this thread's first elem
#pragma unroll
    for (int j = 0; j < 4; ++j) {
        if (i0 + j < N_NODES) {
            start[i0 + j] = p;
            cursor[i0 + j] = p;
        }
        p += v[j];
    }
}

__global__ void k_scatter(const int* __restrict__ dst, int* __restrict__ cursor,
                          int* __restrict__ eidx) {
    int e = blockIdx.x * blockDim.x + threadIdx.x;
    if (e < E_EDGES) {
        int d = dst[e];
        int p = atomicAdd(&cursor[d], 1);
        eidx[p] = e;
    }
}

// ---------------------------------------------------------------------------
// aggregation: one wave per destination node.
// lane -> (head g = lane>>4, dims 2*(lane&15)..+1); out col pair = lane*2.
// out[n] = sum_e exp(lrelu(el[src]+er[n])) * h[src] / sum_e exp(...)
// (softmax shift-invariance: max-subtraction dropped; |logit| <= ~6)
// ---------------------------------------------------------------------------
__global__ __launch_bounds__(256) void k_aggr(const float* __restrict__ h,
                                              const float* __restrict__ el,
                                              const float* __restrict__ er,
                                              const int* __restrict__ src,
                                              const int* __restrict__ start,
                                              const int* __restrict__ deg,
                                              const int* __restrict__ eidx,
                                              float* __restrict__ out) {
    int n = blockIdx.x * 4 + (threadIdx.x >> 6);
    int lane = threadIdx.x & 63;
    int g = lane >> 4;
    int d = deg[n];
    int s0 = start[n];
    float ern = er[n * 4 + g];
    float accx = 0.f, accy = 0.f, s = 0.f;
    for (int i = 0; i < d; ++i) {
        int e = eidx[s0 + i];
        int sv = src[e];
        float x = el[sv * 4 + g] + ern;
        x = x > 0.f ? x : 0.2f * x;
        float w = __expf(x);
        float2 hv = reinterpret_cast<const float2*>(h + (size_t)sv * 128)[lane];
        accx += w * hv.x;
        accy += w * hv.y;
        s += w;
    }
    float inv = (d > 0) ? 1.0f / s : 0.0f;
    reinterpret_cast<float2*>(out + (size_t)n * 128)[lane] = make_float2(accx * inv, accy * inv);
}

// ---------------------------------------------------------------------------
extern "C" void kernel_launch(void* const* d_in, const int* in_sizes, int n_in,
                              void* d_out, int out_size, void* d_ws, size_t ws_size,
                              hipStream_t stream) {
    const float* feat   = (const float*)d_in[0];
    const float* W      = (const float*)d_in[1];
    const float* attn_l = (const float*)d_in[2];
    const float* attn_r = (const float*)d_in[3];
    const int*   src    = (const int*)d_in[4];
    const int*   dst    = (const int*)d_in[5];
    float* out = (float*)d_out;

    float* h  = (float*)d_ws;                          // N*128
    float* el = h + (size_t)N_NODES * 128;             // N*4
    float* er = el + (size_t)N_NODES * 4;              // N*4
    int* deg    = (int*)(er + (size_t)N_NODES * 4);    // N
    int* start  = deg + N_NODES;                       // N
    int* cursor = start + N_NODES;                     // N
    int* eidx   = cursor + N_NODES;                    // E
    int* aux    = eidx + E_EDGES;                      // 128

    hipMemsetAsync(deg, 0, N_NODES * sizeof(int), stream);

    k_gemm<<<N_NODES / 32, 256, 0, stream>>>(feat, W, h);
    k_el_er<<<(N_NODES * 4 + 255) / 256, 256, 0, stream>>>(h, attn_l, attn_r, el, er);
    k_hist<<<(E_EDGES + 255) / 256, 256, 0, stream>>>(dst, deg);
    k_bsum<<<NBLK, 256, 0, stream>>>(deg, aux);
    k_scanaux<<<1, 128, 0, stream>>>(aux);
    k_bscan<<<NBLK, 256, 0, stream>>>(deg, aux, start, cursor);
    k_scatter<<<(E_EDGES + 255) / 256, 256, 0, stream>>>(dst, cursor, eidx);
    k_aggr<<<N_NODES / 4, 256, 0, stream>>>(h, el, er, src, start, deg, eidx, out);
}

// Round 2
// 409.517 us; speedup vs baseline: 1.3209x; 1.3209x over previous
//
#include <hip/hip_runtime.h>

constexpr int N_NODES = 100000;
constexpr int E_EDGES = 1600000;
constexpr int NBLK    = (N_NODES + 1023) / 1024;   // 98 scan blocks

// ---------------------------------------------------------------------------
// GEMM: h[N,128] = feat[N,128] @ W[128,128]^T
// ---------------------------------------------------------------------------
__global__ __launch_bounds__(256, 2) void k_gemm(const float* __restrict__ feat,
                                                 const float* __restrict__ W,
                                                 float* __restrict__ h) {
    __shared__ float Wt[128 * 128];  // Wt[k*128 + c]
    __shared__ float ft[128 * 32];   // ft[k*32 + r]
    const int tid = threadIdx.x;
    const int row0 = blockIdx.x * 32;

#pragma unroll
    for (int m = 0; m < 16; ++m) {
        int chunk = m * 256 + tid;
        int c = chunk & 127;
        int kq = chunk >> 7;
        float4 w = reinterpret_cast<const float4*>(W)[c * 32 + kq];
        Wt[(4 * kq + 0) * 128 + c] = w.x;
        Wt[(4 * kq + 1) * 128 + c] = w.y;
        Wt[(4 * kq + 2) * 128 + c] = w.z;
        Wt[(4 * kq + 3) * 128 + c] = w.w;
    }
#pragma unroll
    for (int m = 0; m < 4; ++m) {
        int chunk = m * 256 + tid;
        int r = chunk & 31;
        int kq = chunk >> 5;
        float4 f = reinterpret_cast<const float4*>(feat)[(size_t)(row0 + r) * 32 + kq];
        ft[(4 * kq + 0) * 32 + r] = f.x;
        ft[(4 * kq + 1) * 32 + r] = f.y;
        ft[(4 * kq + 2) * 32 + r] = f.z;
        ft[(4 * kq + 3) * 32 + r] = f.w;
    }
    __syncthreads();

    const int tc = tid & 31;
    const int tr = tid >> 5;
    float acc[4][4] = {};

#pragma unroll 4
    for (int k = 0; k < 128; ++k) {
        float4 bv = *reinterpret_cast<const float4*>(&Wt[k * 128 + tc * 4]);
        float4 av = *reinterpret_cast<const float4*>(&ft[k * 32 + tr * 4]);
        float a[4] = {av.x, av.y, av.z, av.w};
        float b[4] = {bv.x, bv.y, bv.z, bv.w};
#pragma unroll
        for (int r = 0; r < 4; ++r)
#pragma unroll
            for (int c = 0; c < 4; ++c)
                acc[r][c] += a[r] * b[c];
    }

#pragma unroll
    for (int r = 0; r < 4; ++r) {
        float4 o = make_float4(acc[r][0], acc[r][1], acc[r][2], acc[r][3]);
        *reinterpret_cast<float4*>(&h[(size_t)(row0 + tr * 4 + r) * 128 + tc * 4]) = o;
    }
}

// ---------------------------------------------------------------------------
// el/er: per (node, head) dot of h row-slice with attn vectors
// ---------------------------------------------------------------------------
__global__ void k_el_er(const float* __restrict__ h,
                        const float* __restrict__ attn_l,
                        const float* __restrict__ attn_r,
                        float* __restrict__ el, float* __restrict__ er) {
    int t = blockIdx.x * blockDim.x + threadIdx.x;
    if (t >= N_NODES * 4) return;
    int g = t & 3;
    int n = t >> 2;
    const float4* hp = reinterpret_cast<const float4*>(h + (size_t)n * 128 + g * 32);
    const float4* al = reinterpret_cast<const float4*>(attn_l + g * 32);
    const float4* ar = reinterpret_cast<const float4*>(attn_r + g * 32);
    float sl = 0.f, sr = 0.f;
#pragma unroll
    for (int q = 0; q < 8; ++q) {
        float4 hv = hp[q];
        float4 a = al[q];
        float4 b = ar[q];
        sl += hv.x * a.x + hv.y * a.y + hv.z * a.z + hv.w * a.w;
        sr += hv.x * b.x + hv.y * b.y + hv.z * b.z + hv.w * b.w;
    }
    el[t] = sl;
    er[t] = sr;
}

// ---------------------------------------------------------------------------
// counting sort of edges by dst: histogram -> exclusive scan -> scatter
// ---------------------------------------------------------------------------
__global__ void k_hist(const int* __restrict__ dst, int* __restrict__ deg) {
    int e = blockIdx.x * blockDim.x + threadIdx.x;
    if (e < E_EDGES) atomicAdd(&deg[dst[e]], 1);
}

__global__ void k_bsum(const int* __restrict__ deg, int* __restrict__ aux) {
    int tid = threadIdx.x;
    int i0 = blockIdx.x * 1024 + tid * 4;
    int sum = 0;
#pragma unroll
    for (int j = 0; j < 4; ++j)
        if (i0 + j < N_NODES) sum += deg[i0 + j];
#pragma unroll
    for (int m = 32; m; m >>= 1) sum += __shfl_xor(sum, m, 64);
    __shared__ int wsums[4];
    if ((tid & 63) == 0) wsums[tid >> 6] = sum;
    __syncthreads();
    if (tid == 0) aux[blockIdx.x] = wsums[0] + wsums[1] + wsums[2] + wsums[3];
}

__global__ void k_scanaux(int* __restrict__ aux) {
    __shared__ int s[128];
    int i = threadIdx.x;
    int v = (i < NBLK) ? aux[i] : 0;
    s[i] = v;
    __syncthreads();
#pragma unroll
    for (int d = 1; d < 128; d <<= 1) {
        int t = (i >= d) ? s[i - d] : 0;
        __syncthreads();
        s[i] += t;
        __syncthreads();
    }
    if (i < NBLK) aux[i] = s[i] - v;  // exclusive
}

__global__ void k_bscan(const int* __restrict__ deg, const int* __restrict__ aux,
                        int* __restrict__ start, int* __restrict__ cursor) {
    int tid = threadIdx.x;
    int lane = tid & 63;
    int wid = tid >> 6;
    int i0 = blockIdx.x * 1024 + tid * 4;
    int v[4];
#pragma unroll
    for (int j = 0; j < 4; ++j)
        v[j] = (i0 + j < N_NODES) ? deg[i0 + j] : 0;
    int tsum = v[0] + v[1] + v[2] + v[3];
    int x = tsum;
#pragma unroll
    for (int d = 1; d < 64; d <<= 1) {
        int t = __shfl_up(x, d, 64);
        if (lane >= d) x += t;
    }
    __shared__ int wsums[4];
    if (lane == 63) wsums[wid] = x;
    __syncthreads();
    int base = aux[blockIdx.x];
#pragma unroll
    for (int w = 0; w < 4; ++w)
        if (w < wid) base += wsums[w];
    int p = base + x - tsum;
#pragma unroll
    for (int j = 0; j < 4; ++j) {
        if (i0 + j < N_NODES) {
            start[i0 + j] = p;
            cursor[i0 + j] = p;
        }
        p += v[j];
    }
}

// scatter: writes SORTED SOURCE IDS directly (removes one indirection in aggr)
__global__ void k_scatter(const int* __restrict__ src, const int* __restrict__ dst,
                          int* __restrict__ cursor, int* __restrict__ ssrc) {
    int e = blockIdx.x * blockDim.x + threadIdx.x;
    if (e < E_EDGES) {
        int d = dst[e];
        int p = atomicAdd(&cursor[d], 1);
        ssrc[p] = src[e];
    }
}

// ---------------------------------------------------------------------------
// aggregation: one wave per destination node, 4 edges in flight.
// lane -> (head g = lane>>4, dims 2*(lane&15)..+1 within head g's 32-col slice
//          via float2 at col offset lane*2).
// ---------------------------------------------------------------------------
__global__ __launch_bounds__(256) void k_aggr(const float* __restrict__ h,
                                              const float* __restrict__ el,
                                              const float* __restrict__ er,
                                              const int* __restrict__ ssrc,
                                              const int* __restrict__ start,
                                              const int* __restrict__ deg,
                                              float* __restrict__ out) {
    int n = blockIdx.x * 4 + (threadIdx.x >> 6);
    int lane = threadIdx.x & 63;
    int g = lane >> 4;
    int d = deg[n];
    int s0 = start[n];
    float ern = er[n * 4 + g];

    float ax0 = 0.f, ay0 = 0.f, sw0 = 0.f;
    float ax1 = 0.f, ay1 = 0.f, sw1 = 0.f;
    float ax2 = 0.f, ay2 = 0.f, sw2 = 0.f;
    float ax3 = 0.f, ay3 = 0.f, sw3 = 0.f;

    int i = 0;
    for (; i + 4 <= d; i += 4) {
        int p = s0 + i;
        // issue all independent loads first (4x MLP)
        int v0 = ssrc[p + 0];
        int v1 = ssrc[p + 1];
        int v2 = ssrc[p + 2];
        int v3 = ssrc[p + 3];
        float e0 = el[v0 * 4 + g];
        float e1 = el[v1 * 4 + g];
        float e2 = el[v2 * 4 + g];
        float e3 = el[v3 * 4 + g];
        float2 h0 = reinterpret_cast<const float2*>(h + (size_t)v0 * 128)[lane];
        float2 h1 = reinterpret_cast<const float2*>(h + (size_t)v1 * 128)[lane];
        float2 h2 = reinterpret_cast<const float2*>(h + (size_t)v2 * 128)[lane];
        float2 h3 = reinterpret_cast<const float2*>(h + (size_t)v3 * 128)[lane];

        float x0 = e0 + ern; x0 = x0 > 0.f ? x0 : 0.2f * x0; float w0 = __expf(x0);
        float x1 = e1 + ern; x1 = x1 > 0.f ? x1 : 0.2f * x1; float w1 = __expf(x1);
        float x2 = e2 + ern; x2 = x2 > 0.f ? x2 : 0.2f * x2; float w2 = __expf(x2);
        float x3 = e3 + ern; x3 = x3 > 0.f ? x3 : 0.2f * x3; float w3 = __expf(x3);

        ax0 += w0 * h0.x; ay0 += w0 * h0.y; sw0 += w0;
        ax1 += w1 * h1.x; ay1 += w1 * h1.y; sw1 += w1;
        ax2 += w2 * h2.x; ay2 += w2 * h2.y; sw2 += w2;
        ax3 += w3 * h3.x; ay3 += w3 * h3.y; sw3 += w3;
    }
    for (; i < d; ++i) {
        int v = ssrc[s0 + i];
        float e0 = el[v * 4 + g];
        float2 hv = reinterpret_cast<const float2*>(h + (size_t)v * 128)[lane];
        float x = e0 + ern; x = x > 0.f ? x : 0.2f * x; float w = __expf(x);
        ax0 += w * hv.x; ay0 += w * hv.y; sw0 += w;
    }

    float ax = (ax0 + ax1) + (ax2 + ax3);
    float ay = (ay0 + ay1) + (ay2 + ay3);
    float sw = (sw0 + sw1) + (sw2 + sw3);
    float inv = (d > 0) ? 1.0f / sw : 0.0f;
    reinterpret_cast<float2*>(out + (size_t)n * 128)[lane] = make_float2(ax * inv, ay * inv);
}

// ---------------------------------------------------------------------------
extern "C" void kernel_launch(void* const* d_in, const int* in_sizes, int n_in,
                              void* d_out, int out_size, void* d_ws, size_t ws_size,
                              hipStream_t stream) {
    const float* feat   = (const float*)d_in[0];
    const float* W      = (const float*)d_in[1];
    const float* attn_l = (const float*)d_in[2];
    const float* attn_r = (const float*)d_in[3];
    const int*   src    = (const int*)d_in[4];
    const int*   dst    = (const int*)d_in[5];
    float* out = (float*)d_out;

    float* h  = (float*)d_ws;                          // N*128
    float* el = h + (size_t)N_NODES * 128;             // N*4
    float* er = el + (size_t)N_NODES * 4;              // N*4
    int* deg    = (int*)(er + (size_t)N_NODES * 4);    // N
    int* start  = deg + N_NODES;                       // N
    int* cursor = start + N_NODES;                     // N
    int* ssrc   = cursor + N_NODES;                    // E (sorted src ids)
    int* aux    = ssrc + E_EDGES;                      // 128

    hipMemsetAsync(deg, 0, N_NODES * sizeof(int), stream);

    k_gemm<<<N_NODES / 32, 256, 0, stream>>>(feat, W, h);
    k_el_er<<<(N_NODES * 4 + 255) / 256, 256, 0, stream>>>(h, attn_l, attn_r, el, er);
    k_hist<<<(E_EDGES + 255) / 256, 256, 0, stream>>>(dst, deg);
    k_bsum<<<NBLK, 256, 0, stream>>>(deg, aux);
    k_scanaux<<<1, 128, 0, stream>>>(aux);
    k_bscan<<<NBLK, 256, 0, stream>>>(deg, aux, start, cursor);
    k_scatter<<<(E_EDGES + 255) / 256, 256, 0, stream>>>(src, dst, cursor, ssrc);
    k_aggr<<<N_NODES / 4, 256, 0, stream>>>(h, el, er, ssrc, start, deg, out);
}

// Round 3
// 301.239 us; speedup vs baseline: 1.7957x; 1.3594x over previous
//
#include <hip/hip_runtime.h>

constexpr int N_NODES = 100000;
constexpr int E_EDGES = 1600000;
constexpr int NBLK    = (N_NODES + 1023) / 1024;   // 98 scan blocks

typedef _Float16 f16;
typedef _Float16 f16x2 __attribute__((ext_vector_type(2)));
typedef _Float16 f16x4 __attribute__((ext_vector_type(4)));

// ---------------------------------------------------------------------------
// GEMM: h2[N,128](fp16) = feat[N,128] @ W[128,128]^T, fused el/er epilogue.
// 256 threads/block, 32 rows/block. Thread (tr=tid>>5, tc=tid&31) owns
// rows 4tr..+3 x cols 4tc..+3. Head of cols 4tc..4tc+3 is g=tc>>3.
// el[n][g] = sum_c h[n][c]*attn_l[c] -> 8-lane shuffle reduce (tc&7).
// ---------------------------------------------------------------------------
__global__ __launch_bounds__(256, 2) void k_gemm(const float* __restrict__ feat,
                                                 const float* __restrict__ W,
                                                 const float* __restrict__ attn_l,
                                                 const float* __restrict__ attn_r,
                                                 f16* __restrict__ h2,
                                                 float* __restrict__ el,
                                                 float* __restrict__ er) {
    __shared__ float Wt[128 * 128];  // Wt[k*128 + c]
    __shared__ float ft[128 * 32];   // ft[k*32 + r]
    const int tid = threadIdx.x;
    const int row0 = blockIdx.x * 32;

#pragma unroll
    for (int m = 0; m < 16; ++m) {
        int chunk = m * 256 + tid;
        int c = chunk & 127;
        int kq = chunk >> 7;
        float4 w = reinterpret_cast<const float4*>(W)[c * 32 + kq];
        Wt[(4 * kq + 0) * 128 + c] = w.x;
        Wt[(4 * kq + 1) * 128 + c] = w.y;
        Wt[(4 * kq + 2) * 128 + c] = w.z;
        Wt[(4 * kq + 3) * 128 + c] = w.w;
    }
#pragma unroll
    for (int m = 0; m < 4; ++m) {
        int chunk = m * 256 + tid;
        int r = chunk & 31;
        int kq = chunk >> 5;
        float4 f = reinterpret_cast<const float4*>(feat)[(size_t)(row0 + r) * 32 + kq];
        ft[(4 * kq + 0) * 32 + r] = f.x;
        ft[(4 * kq + 1) * 32 + r] = f.y;
        ft[(4 * kq + 2) * 32 + r] = f.z;
        ft[(4 * kq + 3) * 32 + r] = f.w;
    }
    __syncthreads();

    const int tc = tid & 31;
    const int tr = tid >> 5;
    float acc[4][4] = {};

#pragma unroll 4
    for (int k = 0; k < 128; ++k) {
        float4 bv = *reinterpret_cast<const float4*>(&Wt[k * 128 + tc * 4]);
        float4 av = *reinterpret_cast<const float4*>(&ft[k * 32 + tr * 4]);
        float a[4] = {av.x, av.y, av.z, av.w};
        float b[4] = {bv.x, bv.y, bv.z, bv.w};
#pragma unroll
        for (int r = 0; r < 4; ++r)
#pragma unroll
            for (int c = 0; c < 4; ++c)
                acc[r][c] += a[r] * b[c];
    }

    // epilogue: fp16 store + fused el/er
    const int g = tc >> 3;
    float4 al = reinterpret_cast<const float4*>(attn_l)[tc];
    float4 ar = reinterpret_cast<const float4*>(attn_r)[tc];
#pragma unroll
    for (int r = 0; r < 4; ++r) {
        int row = row0 + tr * 4 + r;
        f16x4 hv;
        hv.x = (f16)acc[r][0]; hv.y = (f16)acc[r][1];
        hv.z = (f16)acc[r][2]; hv.w = (f16)acc[r][3];
        *reinterpret_cast<f16x4*>(&h2[(size_t)row * 128 + tc * 4]) = hv;

        float sl = acc[r][0] * al.x + acc[r][1] * al.y + acc[r][2] * al.z + acc[r][3] * al.w;
        float sr = acc[r][0] * ar.x + acc[r][1] * ar.y + acc[r][2] * ar.z + acc[r][3] * ar.w;
        sl += __shfl_xor(sl, 1, 64); sr += __shfl_xor(sr, 1, 64);
        sl += __shfl_xor(sl, 2, 64); sr += __shfl_xor(sr, 2, 64);
        sl += __shfl_xor(sl, 4, 64); sr += __shfl_xor(sr, 4, 64);
        if ((tc & 7) == 0) {
            el[row * 4 + g] = sl;
            er[row * 4 + g] = sr;
        }
    }
}

// ---------------------------------------------------------------------------
// counting sort of edges by dst: histogram -> exclusive scan -> scatter
// ---------------------------------------------------------------------------
__global__ void k_hist(const int* __restrict__ dst, int* __restrict__ deg) {
    int e = blockIdx.x * blockDim.x + threadIdx.x;
    if (e < E_EDGES) atomicAdd(&deg[dst[e]], 1);
}

__global__ void k_bsum(const int* __restrict__ deg, int* __restrict__ aux) {
    int tid = threadIdx.x;
    int i0 = blockIdx.x * 1024 + tid * 4;
    int sum = 0;
#pragma unroll
    for (int j = 0; j < 4; ++j)
        if (i0 + j < N_NODES) sum += deg[i0 + j];
#pragma unroll
    for (int m = 32; m; m >>= 1) sum += __shfl_xor(sum, m, 64);
    __shared__ int wsums[4];
    if ((tid & 63) == 0) wsums[tid >> 6] = sum;
    __syncthreads();
    if (tid == 0) aux[blockIdx.x] = wsums[0] + wsums[1] + wsums[2] + wsums[3];
}

__global__ void k_scanaux(int* __restrict__ aux) {
    __shared__ int s[128];
    int i = threadIdx.x;
    int v = (i < NBLK) ? aux[i] : 0;
    s[i] = v;
    __syncthreads();
#pragma unroll
    for (int d = 1; d < 128; d <<= 1) {
        int t = (i >= d) ? s[i - d] : 0;
        __syncthreads();
        s[i] += t;
        __syncthreads();
    }
    if (i < NBLK) aux[i] = s[i] - v;  // exclusive
}

__global__ void k_bscan(const int* __restrict__ deg, const int* __restrict__ aux,
                        int* __restrict__ start, int* __restrict__ cursor) {
    int tid = threadIdx.x;
    int lane = tid & 63;
    int wid = tid >> 6;
    int i0 = blockIdx.x * 1024 + tid * 4;
    int v[4];
#pragma unroll
    for (int j = 0; j < 4; ++j)
        v[j] = (i0 + j < N_NODES) ? deg[i0 + j] : 0;
    int tsum = v[0] + v[1] + v[2] + v[3];
    int x = tsum;
#pragma unroll
    for (int d = 1; d < 64; d <<= 1) {
        int t = __shfl_up(x, d, 64);
        if (lane >= d) x += t;
    }
    __shared__ int wsums[4];
    if (lane == 63) wsums[wid] = x;
    __syncthreads();
    int base = aux[blockIdx.x];
#pragma unroll
    for (int w = 0; w < 4; ++w)
        if (w < wid) base += wsums[w];
    int p = base + x - tsum;
#pragma unroll
    for (int j = 0; j < 4; ++j) {
        if (i0 + j < N_NODES) {
            start[i0 + j] = p;
            cursor[i0 + j] = p;
        }
        p += v[j];
    }
}

// ---------------------------------------------------------------------------
// scatter + edge-weight precompute: one 16B record per edge at its sorted slot.
// rec = { fp16 w[4] (packed in .x,.y), src id (.z bitcast), 0 }
// ---------------------------------------------------------------------------
__global__ void k_scatter(const int* __restrict__ src, const int* __restrict__ dst,
                          const float* __restrict__ el, const float* __restrict__ er,
                          int* __restrict__ cursor, float4* __restrict__ rec) {
    int e = blockIdx.x * blockDim.x + threadIdx.x;
    if (e >= E_EDGES) return;
    int s = src[e];
    int d = dst[e];
    float4 a = reinterpret_cast<const float4*>(el)[s];
    float4 b = reinterpret_cast<const float4*>(er)[d];
    float x0 = a.x + b.x; x0 = x0 > 0.f ? x0 : 0.2f * x0;
    float x1 = a.y + b.y; x1 = x1 > 0.f ? x1 : 0.2f * x1;
    float x2 = a.z + b.z; x2 = x2 > 0.f ? x2 : 0.2f * x2;
    float x3 = a.w + b.w; x3 = x3 > 0.f ? x3 : 0.2f * x3;
    f16x2 p01 = {(f16)__expf(x0), (f16)__expf(x1)};
    f16x2 p23 = {(f16)__expf(x2), (f16)__expf(x3)};
    int p = atomicAdd(&cursor[d], 1);
    float4 r;
    r.x = __builtin_bit_cast(float, p01);
    r.y = __builtin_bit_cast(float, p23);
    r.z = __int_as_float(s);
    r.w = 0.f;
    rec[p] = r;
}

// ---------------------------------------------------------------------------
// aggregation: one wave per destination node, 4 edges in flight, no tail.
// lane -> head g = lane>>4, out col pair lane*2. h2 gather = 256B/row (fp16).
// ---------------------------------------------------------------------------
__device__ __forceinline__ float unpack_w(const float4& r, int g) {
    unsigned int u = __float_as_uint((g & 2) ? r.y : r.x);
    unsigned short hw = (g & 1) ? (unsigned short)(u >> 16) : (unsigned short)(u & 0xffff);
    return (float)__builtin_bit_cast(f16, hw);
}

__global__ __launch_bounds__(256) void k_aggr(const f16* __restrict__ h2,
                                              const float4* __restrict__ rec,
                                              const int* __restrict__ start,
                                              const int* __restrict__ deg,
                                              float* __restrict__ out) {
    int n = blockIdx.x * 4 + (threadIdx.x >> 6);
    int lane = threadIdx.x & 63;
    int g = lane >> 4;
    int d = deg[n];
    int s0 = start[n];

    float ax0 = 0.f, ay0 = 0.f, sw0 = 0.f;
    float ax1 = 0.f, ay1 = 0.f, sw1 = 0.f;
    float ax2 = 0.f, ay2 = 0.f, sw2 = 0.f;
    float ax3 = 0.f, ay3 = 0.f, sw3 = 0.f;

    for (int i = 0; i < d; i += 4) {
        bool v1 = (i + 1) < d, v2 = (i + 2) < d, v3 = (i + 3) < d;
        float4 r0 = rec[s0 + i];
        float4 r1 = rec[s0 + (v1 ? i + 1 : 0)];
        float4 r2 = rec[s0 + (v2 ? i + 2 : 0)];
        float4 r3 = rec[s0 + (v3 ? i + 3 : 0)];
        int n0 = __float_as_int(r0.z);
        int n1 = __float_as_int(r1.z);
        int n2 = __float_as_int(r2.z);
        int n3 = __float_as_int(r3.z);
        f16x2 q0 = reinterpret_cast<const f16x2*>(h2 + (size_t)n0 * 128)[lane];
        f16x2 q1 = reinterpret_cast<const f16x2*>(h2 + (size_t)n1 * 128)[lane];
        f16x2 q2 = reinterpret_cast<const f16x2*>(h2 + (size_t)n2 * 128)[lane];
        f16x2 q3 = reinterpret_cast<const f16x2*>(h2 + (size_t)n3 * 128)[lane];

        float w0 = unpack_w(r0, g);
        float w1 = v1 ? unpack_w(r1, g) : 0.f;
        float w2 = v2 ? unpack_w(r2, g) : 0.f;
        float w3 = v3 ? unpack_w(r3, g) : 0.f;

        ax0 += w0 * (float)q0.x; ay0 += w0 * (float)q0.y; sw0 += w0;
        ax1 += w1 * (float)q1.x; ay1 += w1 * (float)q1.y; sw1 += w1;
        ax2 += w2 * (float)q2.x; ay2 += w2 * (float)q2.y; sw2 += w2;
        ax3 += w3 * (float)q3.x; ay3 += w3 * (float)q3.y; sw3 += w3;
    }

    float ax = (ax0 + ax1) + (ax2 + ax3);
    float ay = (ay0 + ay1) + (ay2 + ay3);
    float sw = (sw0 + sw1) + (sw2 + sw3);
    float inv = (d > 0) ? 1.0f / sw : 0.0f;
    reinterpret_cast<float2*>(out + (size_t)n * 128)[lane] = make_float2(ax * inv, ay * inv);
}

// ---------------------------------------------------------------------------
extern "C" void kernel_launch(void* const* d_in, const int* in_sizes, int n_in,
                              void* d_out, int out_size, void* d_ws, size_t ws_size,
                              hipStream_t stream) {
    const float* feat   = (const float*)d_in[0];
    const float* W      = (const float*)d_in[1];
    const float* attn_l = (const float*)d_in[2];
    const float* attn_r = (const float*)d_in[3];
    const int*   src    = (const int*)d_in[4];
    const int*   dst    = (const int*)d_in[5];
    float* out = (float*)d_out;

    // workspace layout (all 16B-aligned): 55.6 MB total
    f16*   h2     = (f16*)d_ws;                              // N*128 fp16 = 25.6 MB
    float* el     = (float*)(h2 + (size_t)N_NODES * 128);    // N*4
    float* er     = el + (size_t)N_NODES * 4;                // N*4
    int*   deg    = (int*)(er + (size_t)N_NODES * 4);        // N
    int*   start  = deg + N_NODES;                           // N
    int*   cursor = start + N_NODES;                         // N
    float4* rec   = (float4*)(cursor + N_NODES);             // E*16B = 25.6 MB
    int*   aux    = (int*)(rec + E_EDGES);                   // 128

    hipMemsetAsync(deg, 0, N_NODES * sizeof(int), stream);

    k_hist<<<(E_EDGES + 255) / 256, 256, 0, stream>>>(dst, deg);
    k_gemm<<<N_NODES / 32, 256, 0, stream>>>(feat, W, attn_l, attn_r, h2, el, er);
    k_bsum<<<NBLK, 256, 0, stream>>>(deg, aux);
    k_scanaux<<<1, 128, 0, stream>>>(aux);
    k_bscan<<<NBLK, 256, 0, stream>>>(deg, aux, start, cursor);
    k_scatter<<<(E_EDGES + 255) / 256, 256, 0, stream>>>(src, dst, el, er, cursor, rec);
    k_aggr<<<N_NODES / 4, 256, 0, stream>>>(h2, rec, start, deg, out);
}

// Round 4
// 274.255 us; speedup vs baseline: 1.9724x; 1.0984x over previous
//
#include <hip/hip_runtime.h>

constexpr int N_NODES = 100000;
constexpr int E_EDGES = 1600000;
constexpr int NBLK    = (N_NODES + 1023) / 1024;   // 98 scan blocks

typedef _Float16 f16;
typedef _Float16 f16x2 __attribute__((ext_vector_type(2)));
typedef _Float16 f16x8 __attribute__((ext_vector_type(8)));
typedef float f32x4 __attribute__((ext_vector_type(4)));

// ---------------------------------------------------------------------------
// MFMA GEMM: h2[N,128](f16) = feat[N,128] @ W[128,128]^T  + fused el/er.
// Block = 256 thr = 4 waves; block covers 64 rows, wave covers 16 rows x 128 cols.
// Per wave: 8 col-tiles x 4 K-chunks of mfma_f32_16x16x32_f16.
// A-frag: lane l -> feat[row0w + (l&15)][kk*32 + (l>>4)*8 + j]  (cvt f32->f16)
// B-frag: lane l -> W[t*16 + (l&15)][kk*32 + (l>>4)*8 + j] from LDS (f16, swizzled)
// C/D: col = lane&15, row = (lane>>4)*4 + reg.
// ---------------------------------------------------------------------------
__global__ __launch_bounds__(256, 2) void k_gemm(const float* __restrict__ feat,
                                                 const float* __restrict__ W,
                                                 const float* __restrict__ attn_l,
                                                 const float* __restrict__ attn_r,
                                                 f16* __restrict__ h2,
                                                 float* __restrict__ el,
                                                 float* __restrict__ er) {
    __shared__ f16 Wlds[128 * 128];  // 32 KB, row-major [n][k], byte ^= (n&7)<<4
    char* wb = (char*)Wlds;
    const int tid = threadIdx.x;

    // stage W as f16: thread t -> row n = t>>1, k-half = (t&1)*64
    {
        int n = tid >> 1;
        int kh = (tid & 1) * 64;
        const float* wsrc = W + n * 128 + kh;
#pragma unroll
        for (int q = 0; q < 8; ++q) {
            float4 u0 = *reinterpret_cast<const float4*>(wsrc + q * 8);
            float4 u1 = *reinterpret_cast<const float4*>(wsrc + q * 8 + 4);
            f16x8 v;
            v[0] = (f16)u0.x; v[1] = (f16)u0.y; v[2] = (f16)u0.z; v[3] = (f16)u0.w;
            v[4] = (f16)u1.x; v[5] = (f16)u1.y; v[6] = (f16)u1.z; v[7] = (f16)u1.w;
            unsigned byte = (unsigned)(n * 256 + kh * 2 + q * 16) ^ ((n & 7) << 4);
            *reinterpret_cast<f16x8*>(wb + byte) = v;
        }
    }
    __syncthreads();

    const int wav  = tid >> 6;
    const int lane = tid & 63;
    const int la = lane & 15;
    const int lb = lane >> 4;
    const int row0w = blockIdx.x * 64 + wav * 16;

    // A fragments (4 K-chunks)
    f16x8 afrag[4];
    {
        int rowA = row0w + la;
        if (rowA >= N_NODES) rowA = N_NODES - 1;
        const float* ap = feat + (size_t)rowA * 128 + lb * 8;
#pragma unroll
        for (int kk = 0; kk < 4; ++kk) {
            float4 u0 = *reinterpret_cast<const float4*>(ap + kk * 32);
            float4 u1 = *reinterpret_cast<const float4*>(ap + kk * 32 + 4);
            f16x8 a;
            a[0] = (f16)u0.x; a[1] = (f16)u0.y; a[2] = (f16)u0.z; a[3] = (f16)u0.w;
            a[4] = (f16)u1.x; a[5] = (f16)u1.y; a[6] = (f16)u1.z; a[7] = (f16)u1.w;
            afrag[kk] = a;
        }
    }

    f32x4 acc[8];
#pragma unroll
    for (int t = 0; t < 8; ++t) acc[t] = (f32x4){0.f, 0.f, 0.f, 0.f};

#pragma unroll
    for (int t = 0; t < 8; ++t) {
        int col = t * 16 + la;
#pragma unroll
        for (int kk = 0; kk < 4; ++kk) {
            unsigned byte = (unsigned)(col * 256 + (kk * 32 + lb * 8) * 2) ^ ((col & 7) << 4);
            f16x8 b = *reinterpret_cast<const f16x8*>(wb + byte);
            acc[t] = __builtin_amdgcn_mfma_f32_16x16x32_f16(afrag[kk], b, acc[t], 0, 0, 0);
        }
    }

    // ---- epilogue: h2 store + fused el/er ----
#pragma unroll
    for (int t = 0; t < 8; ++t) {
#pragma unroll
        for (int r = 0; r < 4; ++r) {
            int row = row0w + lb * 4 + r;
            if (row < N_NODES) h2[(size_t)row * 128 + t * 16 + la] = (f16)acc[t][r];
        }
    }

    float elp[4][4], erp[4][4];
#pragma unroll
    for (int r = 0; r < 4; ++r)
#pragma unroll
        for (int g = 0; g < 4; ++g) { elp[r][g] = 0.f; erp[r][g] = 0.f; }

#pragma unroll
    for (int t = 0; t < 8; ++t) {
        float alv = attn_l[t * 16 + la];
        float arv = attn_r[t * 16 + la];
        int g = t >> 1;
#pragma unroll
        for (int r = 0; r < 4; ++r) {
            elp[r][g] += acc[t][r] * alv;
            erp[r][g] += acc[t][r] * arv;
        }
    }
#pragma unroll
    for (int r = 0; r < 4; ++r)
#pragma unroll
        for (int g = 0; g < 4; ++g) {
            float v = elp[r][g];
            v += __shfl_xor(v, 1, 64); v += __shfl_xor(v, 2, 64);
            v += __shfl_xor(v, 4, 64); v += __shfl_xor(v, 8, 64);
            elp[r][g] = v;
            float u = erp[r][g];
            u += __shfl_xor(u, 1, 64); u += __shfl_xor(u, 2, 64);
            u += __shfl_xor(u, 4, 64); u += __shfl_xor(u, 8, 64);
            erp[r][g] = u;
        }
    if (la == 0) {
#pragma unroll
        for (int r = 0; r < 4; ++r) {
            int row = row0w + lb * 4 + r;
            if (row < N_NODES) {
                *reinterpret_cast<float4*>(el + (size_t)row * 4) =
                    make_float4(elp[r][0], elp[r][1], elp[r][2], elp[r][3]);
                *reinterpret_cast<float4*>(er + (size_t)row * 4) =
                    make_float4(erp[r][0], erp[r][1], erp[r][2], erp[r][3]);
            }
        }
    }
}

// ---------------------------------------------------------------------------
// counting sort of edges by dst: histogram -> exclusive scan -> scatter
// ---------------------------------------------------------------------------
__global__ void k_hist(const int4* __restrict__ dst4, int* __restrict__ deg) {
    int t = blockIdx.x * blockDim.x + threadIdx.x;
    if (t < E_EDGES / 4) {
        int4 d = dst4[t];
        atomicAdd(&deg[d.x], 1);
        atomicAdd(&deg[d.y], 1);
        atomicAdd(&deg[d.z], 1);
        atomicAdd(&deg[d.w], 1);
    }
}

__global__ void k_bsum(const int* __restrict__ deg, int* __restrict__ aux) {
    int tid = threadIdx.x;
    int i0 = blockIdx.x * 1024 + tid * 4;
    int sum = 0;
#pragma unroll
    for (int j = 0; j < 4; ++j)
        if (i0 + j < N_NODES) sum += deg[i0 + j];
#pragma unroll
    for (int m = 32; m; m >>= 1) sum += __shfl_xor(sum, m, 64);
    __shared__ int wsums[4];
    if ((tid & 63) == 0) wsums[tid >> 6] = sum;
    __syncthreads();
    if (tid == 0) aux[blockIdx.x] = wsums[0] + wsums[1] + wsums[2] + wsums[3];
}

__global__ void k_scanaux(int* __restrict__ aux) {
    __shared__ int s[128];
    int i = threadIdx.x;
    int v = (i < NBLK) ? aux[i] : 0;
    s[i] = v;
    __syncthreads();
#pragma unroll
    for (int d = 1; d < 128; d <<= 1) {
        int t = (i >= d) ? s[i - d] : 0;
        __syncthreads();
        s[i] += t;
        __syncthreads();
    }
    if (i < NBLK) aux[i] = s[i] - v;  // exclusive
}

__global__ void k_bscan(const int* __restrict__ deg, const int* __restrict__ aux,
                        int* __restrict__ start, int* __restrict__ cursor) {
    int tid = threadIdx.x;
    int lane = tid & 63;
    int wid = tid >> 6;
    int i0 = blockIdx.x * 1024 + tid * 4;
    int v[4];
#pragma unroll
    for (int j = 0; j < 4; ++j)
        v[j] = (i0 + j < N_NODES) ? deg[i0 + j] : 0;
    int tsum = v[0] + v[1] + v[2] + v[3];
    int x = tsum;
#pragma unroll
    for (int d = 1; d < 64; d <<= 1) {
        int t = __shfl_up(x, d, 64);
        if (lane >= d) x += t;
    }
    __shared__ int wsums[4];
    if (lane == 63) wsums[wid] = x;
    __syncthreads();
    int base = aux[blockIdx.x];
#pragma unroll
    for (int w = 0; w < 4; ++w)
        if (w < wid) base += wsums[w];
    int p = base + x - tsum;
#pragma unroll
    for (int j = 0; j < 4; ++j) {
        if (i0 + j < N_NODES) {
            start[i0 + j] = p;
            cursor[i0 + j] = p;
        }
        p += v[j];
    }
}

// ---------------------------------------------------------------------------
// scatter + edge-weight precompute, 4 edges/thread.
// rec = { f16 w[4] packed in .x,.y ; src id bitcast in .z ; 0 }
// ---------------------------------------------------------------------------
__device__ __forceinline__ float4 mkrec(const float4& a, const float4& b, int s) {
    float x0 = a.x + b.x; x0 = x0 > 0.f ? x0 : 0.2f * x0;
    float x1 = a.y + b.y; x1 = x1 > 0.f ? x1 : 0.2f * x1;
    float x2 = a.z + b.z; x2 = x2 > 0.f ? x2 : 0.2f * x2;
    float x3 = a.w + b.w; x3 = x3 > 0.f ? x3 : 0.2f * x3;
    f16x2 p01 = {(f16)__expf(x0), (f16)__expf(x1)};
    f16x2 p23 = {(f16)__expf(x2), (f16)__expf(x3)};
    float4 r;
    r.x = __builtin_bit_cast(float, p01);
    r.y = __builtin_bit_cast(float, p23);
    r.z = __int_as_float(s);
    r.w = 0.f;
    return r;
}

__global__ void k_scatter(const int4* __restrict__ src4, const int4* __restrict__ dst4,
                          const float* __restrict__ el, const float* __restrict__ er,
                          int* __restrict__ cursor, float4* __restrict__ rec) {
    int t = blockIdx.x * blockDim.x + threadIdx.x;
    if (t >= E_EDGES / 4) return;
    int4 s = src4[t];
    int4 d = dst4[t];
    const float4* el4 = reinterpret_cast<const float4*>(el);
    const float4* er4 = reinterpret_cast<const float4*>(er);
    float4 a0 = el4[s.x], a1 = el4[s.y], a2 = el4[s.z], a3 = el4[s.w];
    float4 b0 = er4[d.x], b1 = er4[d.y], b2 = er4[d.z], b3 = er4[d.w];
    float4 r0 = mkrec(a0, b0, s.x);
    float4 r1 = mkrec(a1, b1, s.y);
    float4 r2 = mkrec(a2, b2, s.z);
    float4 r3 = mkrec(a3, b3, s.w);
    int p0 = atomicAdd(&cursor[d.x], 1);
    int p1 = atomicAdd(&cursor[d.y], 1);
    int p2 = atomicAdd(&cursor[d.z], 1);
    int p3 = atomicAdd(&cursor[d.w], 1);
    rec[p0] = r0;
    rec[p1] = r1;
    rec[p2] = r2;
    rec[p3] = r3;
}

// ---------------------------------------------------------------------------
// aggregation: one wave per dst node, 4 edges in flight, packed-f16 math.
// lane -> head g = lane>>4, out col pair lane*2.
// w broadcast {w,w} via 1 cndmask + 1 v_perm; acc/sum via v_pk_fma/add_f16.
// ---------------------------------------------------------------------------
__global__ __launch_bounds__(256) void k_aggr(const f16* __restrict__ h2,
                                              const float4* __restrict__ rec,
                                              const int* __restrict__ start,
                                              const int* __restrict__ deg,
                                              float* __restrict__ out) {
    int n = blockIdx.x * 4 + (threadIdx.x >> 6);
    int lane = threadIdx.x & 63;
    int g = lane >> 4;
    int d = deg[n];
    int s0 = start[n];
    unsigned sel = (g & 1) ? 0x03020302u : 0x01000100u;  // dup hi16 : dup lo16

    f16x2 ac0 = {0, 0}, ac1 = {0, 0}, ac2 = {0, 0}, ac3 = {0, 0};
    f16x2 sw0 = {0, 0}, sw1 = {0, 0}, sw2 = {0, 0}, sw3 = {0, 0};

    for (int i = 0; i < d; i += 4) {
        bool v1 = (i + 1) < d, v2 = (i + 2) < d, v3 = (i + 3) < d;
        float4 r0 = rec[s0 + i];
        float4 r1 = rec[s0 + (v1 ? i + 1 : 0)];
        float4 r2 = rec[s0 + (v2 ? i + 2 : 0)];
        float4 r3 = rec[s0 + (v3 ? i + 3 : 0)];
        int n0 = __float_as_int(r0.z);
        int n1 = __float_as_int(r1.z);
        int n2 = __float_as_int(r2.z);
        int n3 = __float_as_int(r3.z);
        f16x2 q0 = reinterpret_cast<const f16x2*>(h2 + (size_t)n0 * 128)[lane];
        f16x2 q1 = reinterpret_cast<const f16x2*>(h2 + (size_t)n1 * 128)[lane];
        f16x2 q2 = reinterpret_cast<const f16x2*>(h2 + (size_t)n2 * 128)[lane];
        f16x2 q3 = reinterpret_cast<const f16x2*>(h2 + (size_t)n3 * 128)[lane];

        unsigned u0 = __float_as_uint((g & 2) ? r0.y : r0.x);
        unsigned u1 = v1 ? __float_as_uint((g & 2) ? r1.y : r1.x) : 0u;
        unsigned u2 = v2 ? __float_as_uint((g & 2) ? r2.y : r2.x) : 0u;
        unsigned u3 = v3 ? __float_as_uint((g & 2) ? r3.y : r3.x) : 0u;
        f16x2 w0 = __builtin_bit_cast(f16x2, __builtin_amdgcn_perm(u0, u0, sel));
        f16x2 w1 = __builtin_bit_cast(f16x2, __builtin_amdgcn_perm(u1, u1, sel));
        f16x2 w2 = __builtin_bit_cast(f16x2, __builtin_amdgcn_perm(u2, u2, sel));
        f16x2 w3 = __builtin_bit_cast(f16x2, __builtin_amdgcn_perm(u3, u3, sel));

        ac0 += w0 * q0; sw0 += w0;
        ac1 += w1 * q1; sw1 += w1;
        ac2 += w2 * q2; sw2 += w2;
        ac3 += w3 * q3; sw3 += w3;
    }

    f16x2 ac = (ac0 + ac1) + (ac2 + ac3);
    f16x2 sw = (sw0 + sw1) + (sw2 + sw3);
    float swf = (float)sw[0];
    float inv = (d > 0) ? 1.0f / swf : 0.0f;
    float2 o = make_float2((float)ac[0] * inv, (float)ac[1] * inv);
    reinterpret_cast<float2*>(out + (size_t)n * 128)[lane] = o;
}

// ---------------------------------------------------------------------------
extern "C" void kernel_launch(void* const* d_in, const int* in_sizes, int n_in,
                              void* d_out, int out_size, void* d_ws, size_t ws_size,
                              hipStream_t stream) {
    const float* feat   = (const float*)d_in[0];
    const float* W      = (const float*)d_in[1];
    const float* attn_l = (const float*)d_in[2];
    const float* attn_r = (const float*)d_in[3];
    const int*   src    = (const int*)d_in[4];
    const int*   dst    = (const int*)d_in[5];
    float* out = (float*)d_out;

    // workspace: ~55.7 MB
    f16*   h2     = (f16*)d_ws;                              // N*128 f16 = 25.6 MB
    float* el     = (float*)(h2 + (size_t)N_NODES * 128);    // N*4
    float* er     = el + (size_t)N_NODES * 4;                // N*4
    int*   deg    = (int*)(er + (size_t)N_NODES * 4);        // N
    int*   start  = deg + N_NODES;                           // N
    int*   cursor = start + N_NODES;                         // N
    float4* rec   = (float4*)(cursor + N_NODES);             // E*16B = 25.6 MB
    int*   aux    = (int*)(rec + E_EDGES);                   // 128

    hipMemsetAsync(deg, 0, N_NODES * sizeof(int), stream);

    k_hist<<<(E_EDGES / 4 + 255) / 256, 256, 0, stream>>>((const int4*)dst, deg);
    k_gemm<<<(N_NODES + 63) / 64, 256, 0, stream>>>(feat, W, attn_l, attn_r, h2, el, er);
    k_bsum<<<NBLK, 256, 0, stream>>>(deg, aux);
    k_scanaux<<<1, 128, 0, stream>>>(aux);
    k_bscan<<<NBLK, 256, 0, stream>>>(deg, aux, start, cursor);
    k_scatter<<<(E_EDGES / 4 + 255) / 256, 256, 0, stream>>>((const int4*)src, (const int4*)dst,
                                                             el, er, cursor, rec);
    k_aggr<<<N_NODES / 4, 256, 0, stream>>>(h2, rec, start, deg, out);
}

// Round 5
// 215.127 us; speedup vs baseline: 2.5145x; 1.2749x over previous
//
#include <hip/hip_runtime.h>

constexpr int N_NODES = 100000;
constexpr int E_EDGES = 1600000;
constexpr int NBLK    = (N_NODES + 1023) / 1024;   // 98 scan blocks

typedef _Float16 f16;
typedef _Float16 f16x2 __attribute__((ext_vector_type(2)));
typedef _Float16 f16x8 __attribute__((ext_vector_type(8)));
typedef float f32x4 __attribute__((ext_vector_type(4)));

// ---------------------------------------------------------------------------
// MFMA GEMM: h2[N,128](f16) = feat[N,128] @ W[128,128]^T  + fused el/er.
// Block = 256 thr = 4 waves; block covers 64 rows, wave 16 rows x 128 cols.
// ---------------------------------------------------------------------------
__global__ __launch_bounds__(256, 2) void k_gemm(const float* __restrict__ feat,
                                                 const float* __restrict__ W,
                                                 const float* __restrict__ attn_l,
                                                 const float* __restrict__ attn_r,
                                                 f16* __restrict__ h2,
                                                 float* __restrict__ el,
                                                 float* __restrict__ er) {
    __shared__ f16 Wlds[128 * 128];  // 32 KB, row-major [n][k], byte ^= (n&7)<<4
    char* wb = (char*)Wlds;
    const int tid = threadIdx.x;

    {
        int n = tid >> 1;
        int kh = (tid & 1) * 64;
        const float* wsrc = W + n * 128 + kh;
#pragma unroll
        for (int q = 0; q < 8; ++q) {
            float4 u0 = *reinterpret_cast<const float4*>(wsrc + q * 8);
            float4 u1 = *reinterpret_cast<const float4*>(wsrc + q * 8 + 4);
            f16x8 v;
            v[0] = (f16)u0.x; v[1] = (f16)u0.y; v[2] = (f16)u0.z; v[3] = (f16)u0.w;
            v[4] = (f16)u1.x; v[5] = (f16)u1.y; v[6] = (f16)u1.z; v[7] = (f16)u1.w;
            unsigned byte = (unsigned)(n * 256 + kh * 2 + q * 16) ^ ((n & 7) << 4);
            *reinterpret_cast<f16x8*>(wb + byte) = v;
        }
    }
    __syncthreads();

    const int wav  = tid >> 6;
    const int lane = tid & 63;
    const int la = lane & 15;
    const int lb = lane >> 4;
    const int row0w = blockIdx.x * 64 + wav * 16;

    f16x8 afrag[4];
    {
        int rowA = row0w + la;
        if (rowA >= N_NODES) rowA = N_NODES - 1;
        const float* ap = feat + (size_t)rowA * 128 + lb * 8;
#pragma unroll
        for (int kk = 0; kk < 4; ++kk) {
            float4 u0 = *reinterpret_cast<const float4*>(ap + kk * 32);
            float4 u1 = *reinterpret_cast<const float4*>(ap + kk * 32 + 4);
            f16x8 a;
            a[0] = (f16)u0.x; a[1] = (f16)u0.y; a[2] = (f16)u0.z; a[3] = (f16)u0.w;
            a[4] = (f16)u1.x; a[5] = (f16)u1.y; a[6] = (f16)u1.z; a[7] = (f16)u1.w;
            afrag[kk] = a;
        }
    }

    f32x4 acc[8];
#pragma unroll
    for (int t = 0; t < 8; ++t) acc[t] = (f32x4){0.f, 0.f, 0.f, 0.f};

#pragma unroll
    for (int t = 0; t < 8; ++t) {
        int col = t * 16 + la;
#pragma unroll
        for (int kk = 0; kk < 4; ++kk) {
            unsigned byte = (unsigned)(col * 256 + (kk * 32 + lb * 8) * 2) ^ ((col & 7) << 4);
            f16x8 b = *reinterpret_cast<const f16x8*>(wb + byte);
            acc[t] = __builtin_amdgcn_mfma_f32_16x16x32_f16(afrag[kk], b, acc[t], 0, 0, 0);
        }
    }

    // ---- epilogue: h2 store + fused el/er ----
#pragma unroll
    for (int t = 0; t < 8; ++t) {
#pragma unroll
        for (int r = 0; r < 4; ++r) {
            int row = row0w + lb * 4 + r;
            if (row < N_NODES) h2[(size_t)row * 128 + t * 16 + la] = (f16)acc[t][r];
        }
    }

    float elp[4][4], erp[4][4];
#pragma unroll
    for (int r = 0; r < 4; ++r)
#pragma unroll
        for (int g = 0; g < 4; ++g) { elp[r][g] = 0.f; erp[r][g] = 0.f; }

#pragma unroll
    for (int t = 0; t < 8; ++t) {
        float alv = attn_l[t * 16 + la];
        float arv = attn_r[t * 16 + la];
        int g = t >> 1;
#pragma unroll
        for (int r = 0; r < 4; ++r) {
            elp[r][g] += acc[t][r] * alv;
            erp[r][g] += acc[t][r] * arv;
        }
    }
#pragma unroll
    for (int r = 0; r < 4; ++r)
#pragma unroll
        for (int g = 0; g < 4; ++g) {
            float v = elp[r][g];
            v += __shfl_xor(v, 1, 64); v += __shfl_xor(v, 2, 64);
            v += __shfl_xor(v, 4, 64); v += __shfl_xor(v, 8, 64);
            elp[r][g] = v;
            float u = erp[r][g];
            u += __shfl_xor(u, 1, 64); u += __shfl_xor(u, 2, 64);
            u += __shfl_xor(u, 4, 64); u += __shfl_xor(u, 8, 64);
            erp[r][g] = u;
        }
    if (la == 0) {
#pragma unroll
        for (int r = 0; r < 4; ++r) {
            int row = row0w + lb * 4 + r;
            if (row < N_NODES) {
                *reinterpret_cast<float4*>(el + (size_t)row * 4) =
                    make_float4(elp[r][0], elp[r][1], elp[r][2], elp[r][3]);
                *reinterpret_cast<float4*>(er + (size_t)row * 4) =
                    make_float4(erp[r][0], erp[r][1], erp[r][2], erp[r][3]);
            }
        }
    }
}

// ---------------------------------------------------------------------------
// counting sort by dst: hist (records rank) -> scan -> atomic-free scatter
// ---------------------------------------------------------------------------
__global__ void k_hist(const int* __restrict__ dst, int* __restrict__ deg,
                       int* __restrict__ rank) {
    int e = blockIdx.x * blockDim.x + threadIdx.x;
    if (e < E_EDGES) rank[e] = atomicAdd(&deg[dst[e]], 1);
}

__global__ void k_bsum(const int* __restrict__ deg, int* __restrict__ aux) {
    int tid = threadIdx.x;
    int i0 = blockIdx.x * 1024 + tid * 4;
    int sum = 0;
#pragma unroll
    for (int j = 0; j < 4; ++j)
        if (i0 + j < N_NODES) sum += deg[i0 + j];
#pragma unroll
    for (int m = 32; m; m >>= 1) sum += __shfl_xor(sum, m, 64);
    __shared__ int wsums[4];
    if ((tid & 63) == 0) wsums[tid >> 6] = sum;
    __syncthreads();
    if (tid == 0) aux[blockIdx.x] = wsums[0] + wsums[1] + wsums[2] + wsums[3];
}

__global__ void k_scanaux(int* __restrict__ aux) {
    __shared__ int s[128];
    int i = threadIdx.x;
    int v = (i < NBLK) ? aux[i] : 0;
    s[i] = v;
    __syncthreads();
#pragma unroll
    for (int d = 1; d < 128; d <<= 1) {
        int t = (i >= d) ? s[i - d] : 0;
        __syncthreads();
        s[i] += t;
        __syncthreads();
    }
    if (i < NBLK) aux[i] = s[i] - v;  // exclusive
}

__global__ void k_bscan(const int* __restrict__ deg, const int* __restrict__ aux,
                        int* __restrict__ start) {
    int tid = threadIdx.x;
    int lane = tid & 63;
    int wid = tid >> 6;
    int i0 = blockIdx.x * 1024 + tid * 4;
    int v[4];
#pragma unroll
    for (int j = 0; j < 4; ++j)
        v[j] = (i0 + j < N_NODES) ? deg[i0 + j] : 0;
    int tsum = v[0] + v[1] + v[2] + v[3];
    int x = tsum;
#pragma unroll
    for (int d = 1; d < 64; d <<= 1) {
        int t = __shfl_up(x, d, 64);
        if (lane >= d) x += t;
    }
    __shared__ int wsums[4];
    if (lane == 63) wsums[wid] = x;
    __syncthreads();
    int base = aux[blockIdx.x];
#pragma unroll
    for (int w = 0; w < 4; ++w)
        if (w < wid) base += wsums[w];
    int p = base + x - tsum;
#pragma unroll
    for (int j = 0; j < 4; ++j) {
        if (i0 + j < N_NODES) start[i0 + j] = p;
        p += v[j];
    }
}

// atomic-free scatter: slot = start[dst] + rank, 4B fire-and-forget write
__global__ void k_scatter(const int* __restrict__ src, const int* __restrict__ dst,
                          const int* __restrict__ rank, const int* __restrict__ start,
                          int* __restrict__ ssrc) {
    int e = blockIdx.x * blockDim.x + threadIdx.x;
    if (e < E_EDGES) ssrc[start[dst[e]] + rank[e]] = src[e];
}

// ---------------------------------------------------------------------------
// aggregation: one wave per dst node, 4 edges in flight.
// lane -> head g = lane>>4, out col pair lane*2.
// Per edge: ssrc broadcast load -> {el[s*4+g] (one 16B line/edge, L2),
// h2 row gather (256B)}; w = exp(lrelu(el+er)) on trans pipe; packed-f16 FMA.
// ---------------------------------------------------------------------------
__global__ __launch_bounds__(256) void k_aggr(const f16* __restrict__ h2,
                                              const float* __restrict__ el,
                                              const float* __restrict__ er,
                                              const int* __restrict__ ssrc,
                                              const int* __restrict__ start,
                                              const int* __restrict__ deg,
                                              float* __restrict__ out) {
    int n = blockIdx.x * 4 + (threadIdx.x >> 6);
    int lane = threadIdx.x & 63;
    int g = lane >> 4;
    int d = deg[n];
    int s0 = start[n];
    float ern = er[n * 4 + g];

    f16x2 ac0 = {0, 0}, ac1 = {0, 0}, ac2 = {0, 0}, ac3 = {0, 0};
    f16x2 sw0 = {0, 0}, sw1 = {0, 0}, sw2 = {0, 0}, sw3 = {0, 0};

    for (int i = 0; i < d; i += 4) {
        bool v1 = (i + 1) < d, v2 = (i + 2) < d, v3 = (i + 3) < d;
        // broadcast source ids (1 txn each across the wave)
        int n0 = ssrc[s0 + i];
        int n1 = ssrc[s0 + (v1 ? i + 1 : 0)];
        int n2 = ssrc[s0 + (v2 ? i + 2 : 0)];
        int n3 = ssrc[s0 + (v3 ? i + 3 : 0)];
        // issue all gathers before use
        float e0 = el[n0 * 4 + g];
        float e1 = el[n1 * 4 + g];
        float e2 = el[n2 * 4 + g];
        float e3 = el[n3 * 4 + g];
        f16x2 q0 = reinterpret_cast<const f16x2*>(h2 + (size_t)n0 * 128)[lane];
        f16x2 q1 = reinterpret_cast<const f16x2*>(h2 + (size_t)n1 * 128)[lane];
        f16x2 q2 = reinterpret_cast<const f16x2*>(h2 + (size_t)n2 * 128)[lane];
        f16x2 q3 = reinterpret_cast<const f16x2*>(h2 + (size_t)n3 * 128)[lane];

        float x0 = e0 + ern; x0 = fmaxf(x0, 0.2f * x0);
        float x1 = e1 + ern; x1 = fmaxf(x1, 0.2f * x1);
        float x2 = e2 + ern; x2 = fmaxf(x2, 0.2f * x2);
        float x3 = e3 + ern; x3 = fmaxf(x3, 0.2f * x3);
        float w0 = __expf(x0);
        float w1 = v1 ? __expf(x1) : 0.f;
        float w2 = v2 ? __expf(x2) : 0.f;
        float w3 = v3 ? __expf(x3) : 0.f;

        f16 h0 = (f16)w0; f16x2 wv0 = {h0, h0};
        f16 h1 = (f16)w1; f16x2 wv1 = {h1, h1};
        f16 h2w = (f16)w2; f16x2 wv2 = {h2w, h2w};
        f16 h3 = (f16)w3; f16x2 wv3 = {h3, h3};

        ac0 += wv0 * q0; sw0 += wv0;
        ac1 += wv1 * q1; sw1 += wv1;
        ac2 += wv2 * q2; sw2 += wv2;
        ac3 += wv3 * q3; sw3 += wv3;
    }

    f16x2 ac = (ac0 + ac1) + (ac2 + ac3);
    f16x2 sw = (sw0 + sw1) + (sw2 + sw3);
    float swf = (float)sw[0];
    float inv = (d > 0) ? 1.0f / swf : 0.0f;
    float2 o = make_float2((float)ac[0] * inv, (float)ac[1] * inv);
    reinterpret_cast<float2*>(out + (size_t)n * 128)[lane] = o;
}

// ---------------------------------------------------------------------------
extern "C" void kernel_launch(void* const* d_in, const int* in_sizes, int n_in,
                              void* d_out, int out_size, void* d_ws, size_t ws_size,
                              hipStream_t stream) {
    const float* feat   = (const float*)d_in[0];
    const float* W      = (const float*)d_in[1];
    const float* attn_l = (const float*)d_in[2];
    const float* attn_r = (const float*)d_in[3];
    const int*   src    = (const int*)d_in[4];
    const int*   dst    = (const int*)d_in[5];
    float* out = (float*)d_out;

    // workspace: ~41 MB
    f16*   h2    = (f16*)d_ws;                               // N*128 f16 = 25.6 MB
    float* el    = (float*)(h2 + (size_t)N_NODES * 128);     // N*4
    float* er    = el + (size_t)N_NODES * 4;                 // N*4
    int*   deg   = (int*)(er + (size_t)N_NODES * 4);         // N
    int*   start = deg + N_NODES;                            // N
    int*   rank  = start + N_NODES;                          // E
    int*   ssrc  = rank + E_EDGES;                           // E
    int*   aux   = ssrc + E_EDGES;                           // 128

    hipMemsetAsync(deg, 0, N_NODES * sizeof(int), stream);

    k_hist<<<(E_EDGES + 255) / 256, 256, 0, stream>>>(dst, deg, rank);
    k_gemm<<<(N_NODES + 63) / 64, 256, 0, stream>>>(feat, W, attn_l, attn_r, h2, el, er);
    k_bsum<<<NBLK, 256, 0, stream>>>(deg, aux);
    k_scanaux<<<1, 128, 0, stream>>>(aux);
    k_bscan<<<NBLK, 256, 0, stream>>>(deg, aux, start);
    k_scatter<<<(E_EDGES + 255) / 256, 256, 0, stream>>>(src, dst, rank, start, ssrc);
    k_aggr<<<N_NODES / 4, 256, 0, stream>>>(h2, el, er, ssrc, start, deg, out);
}

// Round 6
// 211.508 us; speedup vs baseline: 2.5575x; 1.0171x over previous
//
#include <hip/hip_runtime.h>

constexpr int N_NODES = 100000;
constexpr int E_EDGES = 1600000;
constexpr int NBLK    = (N_NODES + 1023) / 1024;     // 98 scan blocks
constexpr int GEMM_BLOCKS = (N_NODES + 63) / 64;     // 1563
constexpr int HIST_BLOCKS = (E_EDGES / 4 + 255) / 256; // 1563

typedef _Float16 f16;
typedef _Float16 f16x2 __attribute__((ext_vector_type(2)));
typedef _Float16 f16x8 __attribute__((ext_vector_type(8)));
typedef float f32x4 __attribute__((ext_vector_type(4)));

// ---------------------------------------------------------------------------
// Fused: MFMA GEMM (+el/er epilogue) for blocks < GEMM_BLOCKS,
//        edge histogram + rank for blocks >= GEMM_BLOCKS (independent work).
// ---------------------------------------------------------------------------
__global__ __launch_bounds__(256, 2) void k_gemm_hist(
        const float* __restrict__ feat, const float* __restrict__ W,
        const float* __restrict__ attn_l, const float* __restrict__ attn_r,
        f16* __restrict__ h2, float* __restrict__ el, float* __restrict__ er,
        const int4* __restrict__ dst4, int* __restrict__ deg,
        int4* __restrict__ rank4) {
    __shared__ f16 Wlds[128 * 128];  // 32 KB, row-major [n][k], byte ^= (n&7)<<4

    if (blockIdx.x >= GEMM_BLOCKS) {
        // ---- histogram path ----
        int t = (blockIdx.x - GEMM_BLOCKS) * 256 + threadIdx.x;
        if (t < E_EDGES / 4) {
            int4 d = dst4[t];
            int r0 = atomicAdd(&deg[d.x], 1);
            int r1 = atomicAdd(&deg[d.y], 1);
            int r2 = atomicAdd(&deg[d.z], 1);
            int r3 = atomicAdd(&deg[d.w], 1);
            rank4[t] = make_int4(r0, r1, r2, r3);
        }
        return;
    }

    // ---- GEMM path ----
    char* wb = (char*)Wlds;
    const int tid = threadIdx.x;
    {
        int n = tid >> 1;
        int kh = (tid & 1) * 64;
        const float* wsrc = W + n * 128 + kh;
#pragma unroll
        for (int q = 0; q < 8; ++q) {
            float4 u0 = *reinterpret_cast<const float4*>(wsrc + q * 8);
            float4 u1 = *reinterpret_cast<const float4*>(wsrc + q * 8 + 4);
            f16x8 v;
            v[0] = (f16)u0.x; v[1] = (f16)u0.y; v[2] = (f16)u0.z; v[3] = (f16)u0.w;
            v[4] = (f16)u1.x; v[5] = (f16)u1.y; v[6] = (f16)u1.z; v[7] = (f16)u1.w;
            unsigned byte = (unsigned)(n * 256 + kh * 2 + q * 16) ^ ((n & 7) << 4);
            *reinterpret_cast<f16x8*>(wb + byte) = v;
        }
    }
    __syncthreads();

    const int wav  = tid >> 6;
    const int lane = tid & 63;
    const int la = lane & 15;
    const int lb = lane >> 4;
    const int row0w = blockIdx.x * 64 + wav * 16;

    f16x8 afrag[4];
    {
        int rowA = row0w + la;
        if (rowA >= N_NODES) rowA = N_NODES - 1;
        const float* ap = feat + (size_t)rowA * 128 + lb * 8;
#pragma unroll
        for (int kk = 0; kk < 4; ++kk) {
            float4 u0 = *reinterpret_cast<const float4*>(ap + kk * 32);
            float4 u1 = *reinterpret_cast<const float4*>(ap + kk * 32 + 4);
            f16x8 a;
            a[0] = (f16)u0.x; a[1] = (f16)u0.y; a[2] = (f16)u0.z; a[3] = (f16)u0.w;
            a[4] = (f16)u1.x; a[5] = (f16)u1.y; a[6] = (f16)u1.z; a[7] = (f16)u1.w;
            afrag[kk] = a;
        }
    }

    f32x4 acc[8];
#pragma unroll
    for (int t = 0; t < 8; ++t) acc[t] = (f32x4){0.f, 0.f, 0.f, 0.f};

#pragma unroll
    for (int t = 0; t < 8; ++t) {
        int col = t * 16 + la;
#pragma unroll
        for (int kk = 0; kk < 4; ++kk) {
            unsigned byte = (unsigned)(col * 256 + (kk * 32 + lb * 8) * 2) ^ ((col & 7) << 4);
            f16x8 b = *reinterpret_cast<const f16x8*>(wb + byte);
            acc[t] = __builtin_amdgcn_mfma_f32_16x16x32_f16(afrag[kk], b, acc[t], 0, 0, 0);
        }
    }

#pragma unroll
    for (int t = 0; t < 8; ++t) {
#pragma unroll
        for (int r = 0; r < 4; ++r) {
            int row = row0w + lb * 4 + r;
            if (row < N_NODES) h2[(size_t)row * 128 + t * 16 + la] = (f16)acc[t][r];
        }
    }

    float elp[4][4], erp[4][4];
#pragma unroll
    for (int r = 0; r < 4; ++r)
#pragma unroll
        for (int g = 0; g < 4; ++g) { elp[r][g] = 0.f; erp[r][g] = 0.f; }

#pragma unroll
    for (int t = 0; t < 8; ++t) {
        float alv = attn_l[t * 16 + la];
        float arv = attn_r[t * 16 + la];
        int g = t >> 1;
#pragma unroll
        for (int r = 0; r < 4; ++r) {
            elp[r][g] += acc[t][r] * alv;
            erp[r][g] += acc[t][r] * arv;
        }
    }
#pragma unroll
    for (int r = 0; r < 4; ++r)
#pragma unroll
        for (int g = 0; g < 4; ++g) {
            float v = elp[r][g];
            v += __shfl_xor(v, 1, 64); v += __shfl_xor(v, 2, 64);
            v += __shfl_xor(v, 4, 64); v += __shfl_xor(v, 8, 64);
            elp[r][g] = v;
            float u = erp[r][g];
            u += __shfl_xor(u, 1, 64); u += __shfl_xor(u, 2, 64);
            u += __shfl_xor(u, 4, 64); u += __shfl_xor(u, 8, 64);
            erp[r][g] = u;
        }
    if (la == 0) {
#pragma unroll
        for (int r = 0; r < 4; ++r) {
            int row = row0w + lb * 4 + r;
            if (row < N_NODES) {
                *reinterpret_cast<float4*>(el + (size_t)row * 4) =
                    make_float4(elp[r][0], elp[r][1], elp[r][2], elp[r][3]);
                *reinterpret_cast<float4*>(er + (size_t)row * 4) =
                    make_float4(erp[r][0], erp[r][1], erp[r][2], erp[r][3]);
            }
        }
    }
}

// ---------------------------------------------------------------------------
// scan over PADDED degrees: pdeg = (deg+3)&~3 so every segment is a x4 multiple
// ---------------------------------------------------------------------------
__global__ void k_bsum(const int* __restrict__ deg, int* __restrict__ aux) {
    int tid = threadIdx.x;
    int i0 = blockIdx.x * 1024 + tid * 4;
    int sum = 0;
#pragma unroll
    for (int j = 0; j < 4; ++j)
        if (i0 + j < N_NODES) sum += (deg[i0 + j] + 3) & ~3;
#pragma unroll
    for (int m = 32; m; m >>= 1) sum += __shfl_xor(sum, m, 64);
    __shared__ int wsums[4];
    if ((tid & 63) == 0) wsums[tid >> 6] = sum;
    __syncthreads();
    if (tid == 0) aux[blockIdx.x] = wsums[0] + wsums[1] + wsums[2] + wsums[3];
}

__global__ void k_scanaux(int* __restrict__ aux) {
    __shared__ int s[128];
    int i = threadIdx.x;
    int v = (i < NBLK) ? aux[i] : 0;
    s[i] = v;
    __syncthreads();
#pragma unroll
    for (int d = 1; d < 128; d <<= 1) {
        int t = (i >= d) ? s[i - d] : 0;
        __syncthreads();
        s[i] += t;
        __syncthreads();
    }
    if (i < NBLK) aux[i] = s[i] - v;  // exclusive
}

// bscan: padded prefix -> start; fills pad slots with dummy node; inits dummy
__global__ void k_bscan(const int* __restrict__ deg, const int* __restrict__ aux,
                        int* __restrict__ start, int* __restrict__ ssrc,
                        f16* __restrict__ h2, float* __restrict__ el) {
    if (blockIdx.x == 0 && threadIdx.x == 0) {
        // dummy node N_NODES: zero h2 row, el = -1e4 (-> w = 0)
        float4 z = make_float4(0.f, 0.f, 0.f, 0.f);
        float4* hrow = reinterpret_cast<float4*>(h2 + (size_t)N_NODES * 128);
#pragma unroll
        for (int q = 0; q < 16; ++q) hrow[q] = z;
        *reinterpret_cast<float4*>(el + (size_t)N_NODES * 4) =
            make_float4(-1e4f, -1e4f, -1e4f, -1e4f);
    }
    int tid = threadIdx.x;
    int lane = tid & 63;
    int wid = tid >> 6;
    int i0 = blockIdx.x * 1024 + tid * 4;
    int v[4], pv[4];
#pragma unroll
    for (int j = 0; j < 4; ++j) {
        v[j]  = (i0 + j < N_NODES) ? deg[i0 + j] : 0;
        pv[j] = (v[j] + 3) & ~3;
    }
    int tsum = pv[0] + pv[1] + pv[2] + pv[3];
    int x = tsum;
#pragma unroll
    for (int d = 1; d < 64; d <<= 1) {
        int t = __shfl_up(x, d, 64);
        if (lane >= d) x += t;
    }
    __shared__ int wsums[4];
    if (lane == 63) wsums[wid] = x;
    __syncthreads();
    int base = aux[blockIdx.x];
#pragma unroll
    for (int w = 0; w < 4; ++w)
        if (w < wid) base += wsums[w];
    int p = base + x - tsum;
#pragma unroll
    for (int j = 0; j < 4; ++j) {
        if (i0 + j < N_NODES) {
            start[i0 + j] = p;
            for (int q = v[j]; q < pv[j]; ++q) ssrc[p + q] = N_NODES;  // pad sentinel
        }
        p += pv[j];
    }
}

// atomic-free scatter: slot = start[dst] + rank
__global__ void k_scatter(const int* __restrict__ src, const int* __restrict__ dst,
                          const int* __restrict__ rank, const int* __restrict__ start,
                          int* __restrict__ ssrc) {
    int e = blockIdx.x * blockDim.x + threadIdx.x;
    if (e < E_EDGES) ssrc[start[dst[e]] + rank[e]] = src[e];
}

// ---------------------------------------------------------------------------
// aggregation: ONE WAVE PER NODE (128-thr block = 2 independent waves).
// Segment padded to x4 -> uniform loop, no predication.
// s0 forced to SGPR -> ssrc loads become s_load; src ids land in SGPRs ->
// el/h2 gather addressing is SALU + hoisted lane offset (saddr form).
// ---------------------------------------------------------------------------
__global__ __launch_bounds__(128) void k_aggr(const f16* __restrict__ h2,
                                              const float* __restrict__ el,
                                              const float* __restrict__ er,
                                              const int* __restrict__ ssrc,
                                              const int* __restrict__ start,
                                              const int* __restrict__ deg,
                                              float* __restrict__ out) {
    int n = blockIdx.x * 2 + (threadIdx.x >> 6);
    if (n >= N_NODES) return;
    int lane = threadIdx.x & 63;
    int g = lane >> 4;
    int d = deg[n];
    int pd = (d + 3) & ~3;
    int s0 = __builtin_amdgcn_readfirstlane(start[n]);
    float ern = er[n * 4 + g];

    f16x2 ac0 = {0, 0}, ac1 = {0, 0}, ac2 = {0, 0}, ac3 = {0, 0};
    f16x2 sw0 = {0, 0}, sw1 = {0, 0}, sw2 = {0, 0}, sw3 = {0, 0};

    for (int i = 0; i < pd; i += 4) {
        int n0 = ssrc[s0 + i];
        int n1 = ssrc[s0 + i + 1];
        int n2 = ssrc[s0 + i + 2];
        int n3 = ssrc[s0 + i + 3];
        float e0 = el[(size_t)n0 * 4 + g];
        float e1 = el[(size_t)n1 * 4 + g];
        float e2 = el[(size_t)n2 * 4 + g];
        float e3 = el[(size_t)n3 * 4 + g];
        f16x2 q0 = reinterpret_cast<const f16x2*>(h2 + (size_t)n0 * 128)[lane];
        f16x2 q1 = reinterpret_cast<const f16x2*>(h2 + (size_t)n1 * 128)[lane];
        f16x2 q2 = reinterpret_cast<const f16x2*>(h2 + (size_t)n2 * 128)[lane];
        f16x2 q3 = reinterpret_cast<const f16x2*>(h2 + (size_t)n3 * 128)[lane];

        float x0 = e0 + ern; x0 = fmaxf(x0, 0.2f * x0);
        float x1 = e1 + ern; x1 = fmaxf(x1, 0.2f * x1);
        float x2 = e2 + ern; x2 = fmaxf(x2, 0.2f * x2);
        float x3 = e3 + ern; x3 = fmaxf(x3, 0.2f * x3);
        float w0 = __expf(x0);
        float w1 = __expf(x1);
        float w2 = __expf(x2);
        float w3 = __expf(x3);

        f16 a0 = (f16)w0; f16x2 wv0 = {a0, a0};
        f16 a1 = (f16)w1; f16x2 wv1 = {a1, a1};
        f16 a2 = (f16)w2; f16x2 wv2 = {a2, a2};
        f16 a3 = (f16)w3; f16x2 wv3 = {a3, a3};

        ac0 += wv0 * q0; sw0 += wv0;
        ac1 += wv1 * q1; sw1 += wv1;
        ac2 += wv2 * q2; sw2 += wv2;
        ac3 += wv3 * q3; sw3 += wv3;
    }

    f16x2 ac = (ac0 + ac1) + (ac2 + ac3);
    f16x2 sw = (sw0 + sw1) + (sw2 + sw3);
    float swf = (float)sw[0];
    float inv = (d > 0) ? 1.0f / swf : 0.0f;
    float2 o = make_float2((float)ac[0] * inv, (float)ac[1] * inv);
    reinterpret_cast<float2*>(out + (size_t)n * 128)[lane] = o;
}

// ---------------------------------------------------------------------------
extern "C" void kernel_launch(void* const* d_in, const int* in_sizes, int n_in,
                              void* d_out, int out_size, void* d_ws, size_t ws_size,
                              hipStream_t stream) {
    const float* feat   = (const float*)d_in[0];
    const float* W      = (const float*)d_in[1];
    const float* attn_l = (const float*)d_in[2];
    const float* attn_r = (const float*)d_in[3];
    const int*   src    = (const int*)d_in[4];
    const int*   dst    = (const int*)d_in[5];
    float* out = (float*)d_out;

    // workspace (~45 MB): h2 has one extra dummy row; ssrc has padding slack
    f16*   h2    = (f16*)d_ws;                               // (N+1)*128 f16
    float* el    = (float*)(h2 + (size_t)(N_NODES + 8) * 128); // (N+1)*4
    float* er    = el + (size_t)(N_NODES + 4) * 4;           // N*4
    int*   deg   = (int*)(er + (size_t)N_NODES * 4);         // N
    int*   start = deg + N_NODES;                            // N
    int*   rank  = start + N_NODES;                          // E
    int*   ssrc  = rank + E_EDGES;                           // E + 3N (padded)
    int*   aux   = ssrc + E_EDGES + 3 * N_NODES + 64;        // 128

    hipMemsetAsync(deg, 0, N_NODES * sizeof(int), stream);

    k_gemm_hist<<<GEMM_BLOCKS + HIST_BLOCKS, 256, 0, stream>>>(
        feat, W, attn_l, attn_r, h2, el, er, (const int4*)dst, deg, (int4*)rank);
    k_bsum<<<NBLK, 256, 0, stream>>>(deg, aux);
    k_scanaux<<<1, 128, 0, stream>>>(aux);
    k_bscan<<<NBLK, 256, 0, stream>>>(deg, aux, start, ssrc, h2, el);
    k_scatter<<<(E_EDGES + 255) / 256, 256, 0, stream>>>(src, dst, rank, start, ssrc);
    k_aggr<<<(N_NODES + 1) / 2, 128, 0, stream>>>(h2, el, er, ssrc, start, deg, out);
}